// Round 1
// baseline (838.673 us; speedup 1.0000x reference)
//
#include <hip/hip_runtime.h>

#define M_DIM 16384
#define N_DIM 4096
#define K_DIM 4096
#define BM 128
#define BN 128
#define BK 64

typedef __attribute__((ext_vector_type(4))) float f32x4;
typedef __attribute__((ext_vector_type(8))) short bf16x8;
typedef __attribute__((ext_vector_type(4))) int i32x4;

__device__ __forceinline__ short f2bf(float f) {
    unsigned int u = __builtin_bit_cast(unsigned int, f);
    u += 0x7FFFu + ((u >> 16) & 1u);   // RNE to bf16
    return (short)(u >> 16);
}

// fp32 -> bf16, 8 elems/thread, grid-stride
__global__ void cvt_x_kernel(const float* __restrict__ x, short* __restrict__ o, long n) {
    long i = ((long)blockIdx.x * blockDim.x + threadIdx.x) * 8;
    long stride = (long)gridDim.x * blockDim.x * 8;
    for (; i < n; i += stride) {
        f32x4 a = *(const f32x4*)(x + i);
        f32x4 b = *(const f32x4*)(x + i + 4);
        bf16x8 r;
        r[0] = f2bf(a[0]); r[1] = f2bf(a[1]); r[2] = f2bf(a[2]); r[3] = f2bf(a[3]);
        r[4] = f2bf(b[0]); r[5] = f2bf(b[1]); r[6] = f2bf(b[2]); r[7] = f2bf(b[3]);
        *(bf16x8*)(o + i) = r;
    }
}

// int32 (values in [-128,127], exact in bf16) -> bf16
__global__ void cvt_w_kernel(const int* __restrict__ q, short* __restrict__ o, long n) {
    long i = ((long)blockIdx.x * blockDim.x + threadIdx.x) * 8;
    long stride = (long)gridDim.x * blockDim.x * 8;
    for (; i < n; i += stride) {
        i32x4 a = *(const i32x4*)(q + i);
        i32x4 b = *(const i32x4*)(q + i + 4);
        bf16x8 r;
        r[0] = f2bf((float)a[0]); r[1] = f2bf((float)a[1]);
        r[2] = f2bf((float)a[2]); r[3] = f2bf((float)a[3]);
        r[4] = f2bf((float)b[0]); r[5] = f2bf((float)b[1]);
        r[6] = f2bf((float)b[2]); r[7] = f2bf((float)b[3]);
        *(bf16x8*)(o + i) = r;
    }
}

__device__ __forceinline__ void load_lds16(const void* g, void* l) {
    __builtin_amdgcn_global_load_lds((const __attribute__((address_space(1))) void*)g,
                                     (__attribute__((address_space(3))) void*)l, 16, 0, 0);
}

// C[m][n] = sum_k A[m][k] * W[n][k]; epilogue y = acc*scales[n] + bias[n].
// LDS layout per tile: [row 0..127][BK], 128B rows, 16B slot index XOR-swizzled
// with (row&7); swizzle realized by permuting the per-lane GLOBAL source
// (LDS writes stay linear, as global_load_lds requires).
// MODE 0: A,B already bf16 in workspace, staged via global_load_lds dwordx4.
// MODE 1: A fp32 / B int32 staged through registers with in-flight conversion.
template<int MODE>
__global__ __launch_bounds__(256)
void gemm_kernel(const short* __restrict__ A, const short* __restrict__ Bw,
                 const float* __restrict__ Xf, const int* __restrict__ Qw,
                 const float* __restrict__ scales, const float* __restrict__ bias,
                 float* __restrict__ out) {
    __shared__ short a_lds[BM * BK];   // 16 KB
    __shared__ short b_lds[BN * BK];   // 16 KB

    const int tid  = threadIdx.x;
    const int lane = tid & 63;
    const int wid  = tid >> 6;     // 4 waves
    const int wm   = wid >> 1;     // 0..1
    const int wn   = wid & 1;      // 0..1

    const int bn = (blockIdx.x % (N_DIM / BN)) * BN;
    const int bm = (blockIdx.x / (N_DIM / BN)) * BM;

    const int lrow = lane & 15;    // fragment row (A) / col (B)
    const int lkg  = lane >> 4;    // k subgroup

    f32x4 acc[4][4];
#pragma unroll
    for (int i = 0; i < 4; ++i)
#pragma unroll
        for (int j = 0; j < 4; ++j)
            acc[i][j] = (f32x4){0.f, 0.f, 0.f, 0.f};

    for (int k0 = 0; k0 < K_DIM; k0 += BK) {
        if constexpr (MODE == 0) {
            // 16 chunks of 1KB per tile; each wave stages 4 for A, 4 for B.
#pragma unroll
            for (int t = 0; t < 4; ++t) {
                const int c   = t * 4 + wid;          // 0..15
                const int row = (c << 3) + (lane >> 3);
                const int kc  = (lane & 7) ^ ((lane >> 3) & 7); // swizzled k-slot
                load_lds16(A  + (size_t)(bm + row) * K_DIM + k0 + kc * 8, &a_lds[c * 512]);
                load_lds16(Bw + (size_t)(bn + row) * K_DIM + k0 + kc * 8, &b_lds[c * 512]);
            }
        } else {
            // reg staging + convert; 1024 16B-chunks per tile, 4/thread each.
#pragma unroll
            for (int t = 0; t < 4; ++t) {
                const int ch  = t * 256 + tid;        // 0..1023
                const int row = ch >> 3;
                const int kc  = (ch & 7) ^ (row & 7);
                {
                    const float* sa = Xf + (size_t)(bm + row) * K_DIM + k0 + kc * 8;
                    f32x4 a0 = *(const f32x4*)sa;
                    f32x4 a1 = *(const f32x4*)(sa + 4);
                    bf16x8 r;
                    r[0] = f2bf(a0[0]); r[1] = f2bf(a0[1]); r[2] = f2bf(a0[2]); r[3] = f2bf(a0[3]);
                    r[4] = f2bf(a1[0]); r[5] = f2bf(a1[1]); r[6] = f2bf(a1[2]); r[7] = f2bf(a1[3]);
                    *(bf16x8*)&a_lds[ch * 8] = r;
                }
                {
                    const int* sb = Qw + (size_t)(bn + row) * K_DIM + k0 + kc * 8;
                    i32x4 q0 = *(const i32x4*)sb;
                    i32x4 q1 = *(const i32x4*)(sb + 4);
                    bf16x8 r;
                    r[0] = f2bf((float)q0[0]); r[1] = f2bf((float)q0[1]);
                    r[2] = f2bf((float)q0[2]); r[3] = f2bf((float)q0[3]);
                    r[4] = f2bf((float)q1[0]); r[5] = f2bf((float)q1[1]);
                    r[6] = f2bf((float)q1[2]); r[7] = f2bf((float)q1[3]);
                    *(bf16x8*)&b_lds[ch * 8] = r;
                }
            }
        }
        __syncthreads();

#pragma unroll
        for (int ks = 0; ks < 2; ++ks) {
            const int kgl = ks * 4 + lkg;   // 0..7
            bf16x8 af[4], bfr[4];
#pragma unroll
            for (int i = 0; i < 4; ++i) {
                const int am = wm * 64 + i * 16 + lrow;
                af[i]  = *(const bf16x8*)&a_lds[am * 64 + ((kgl ^ (am & 7)) << 3)];
                const int bnn = wn * 64 + i * 16 + lrow;
                bfr[i] = *(const bf16x8*)&b_lds[bnn * 64 + ((kgl ^ (bnn & 7)) << 3)];
            }
#pragma unroll
            for (int i = 0; i < 4; ++i)
#pragma unroll
                for (int j = 0; j < 4; ++j)
                    acc[i][j] = __builtin_amdgcn_mfma_f32_16x16x32_bf16(af[i], bfr[j], acc[i][j], 0, 0, 0);
        }
        __syncthreads();
    }

    // epilogue: y = acc * scales[col] + bias[col]
#pragma unroll
    for (int j = 0; j < 4; ++j) {
        const int col = bn + wn * 64 + j * 16 + lrow;
        const float s  = scales[col];
        const float bb = bias[col];
#pragma unroll
        for (int i = 0; i < 4; ++i) {
            const int row0 = bm + wm * 64 + i * 16 + lkg * 4;
#pragma unroll
            for (int r = 0; r < 4; ++r)
                out[(size_t)(row0 + r) * N_DIM + col] = acc[i][j][r] * s + bb;
        }
    }
}

extern "C" void kernel_launch(void* const* d_in, const int* in_sizes, int n_in,
                              void* d_out, int out_size, void* d_ws, size_t ws_size,
                              hipStream_t stream) {
    const float* x      = (const float*)d_in[0];
    const int*   qw     = (const int*)d_in[1];
    const float* scales = (const float*)d_in[2];
    const float* bias   = (const float*)d_in[3];
    float* out = (float*)d_out;

    const size_t x_elems = (size_t)M_DIM * K_DIM;   // 67108864
    const size_t w_elems = (size_t)N_DIM * K_DIM;   // 16777216
    const size_t need    = (x_elems + w_elems) * sizeof(short);  // 160 MB

    const dim3 grid((M_DIM / BM) * (N_DIM / BN));   // 4096 blocks

    if (ws_size >= need) {
        short* xbf = (short*)d_ws;
        short* wbf = xbf + x_elems;
        cvt_x_kernel<<<4096, 256, 0, stream>>>(x, xbf, (long)x_elems);
        cvt_w_kernel<<<2048, 256, 0, stream>>>(qw, wbf, (long)w_elems);
        gemm_kernel<0><<<grid, 256, 0, stream>>>(xbf, wbf, nullptr, nullptr, scales, bias, out);
    } else {
        gemm_kernel<1><<<grid, 256, 0, stream>>>(nullptr, nullptr, x, qw, scales, bias, out);
    }
}

// Round 2
// 545.642 us; speedup vs baseline: 1.5370x; 1.5370x over previous
//
#include <hip/hip_runtime.h>

#define M_DIM 16384
#define N_DIM 4096
#define K_DIM 4096
#define NT 64            // K_DIM / BK, BK = 64

typedef __attribute__((ext_vector_type(4))) float f32x4;
typedef __attribute__((ext_vector_type(8))) short bf16x8;
typedef __attribute__((ext_vector_type(4))) int i32x4;

__device__ __forceinline__ short f2bf(float f) {
    unsigned int u = __builtin_bit_cast(unsigned int, f);
    u += 0x7FFFu + ((u >> 16) & 1u);   // RNE to bf16
    return (short)(u >> 16);
}

__global__ void cvt_x_kernel(const float* __restrict__ x, short* __restrict__ o, long n) {
    long i = ((long)blockIdx.x * blockDim.x + threadIdx.x) * 8;
    long stride = (long)gridDim.x * blockDim.x * 8;
    for (; i < n; i += stride) {
        f32x4 a = *(const f32x4*)(x + i);
        f32x4 b = *(const f32x4*)(x + i + 4);
        bf16x8 r;
        r[0] = f2bf(a[0]); r[1] = f2bf(a[1]); r[2] = f2bf(a[2]); r[3] = f2bf(a[3]);
        r[4] = f2bf(b[0]); r[5] = f2bf(b[1]); r[6] = f2bf(b[2]); r[7] = f2bf(b[3]);
        *(bf16x8*)(o + i) = r;
    }
}

__global__ void cvt_w_kernel(const int* __restrict__ q, short* __restrict__ o, long n) {
    long i = ((long)blockIdx.x * blockDim.x + threadIdx.x) * 8;
    long stride = (long)gridDim.x * blockDim.x * 8;
    for (; i < n; i += stride) {
        i32x4 a = *(const i32x4*)(q + i);
        i32x4 b = *(const i32x4*)(q + i + 4);
        bf16x8 r;
        r[0] = f2bf((float)a[0]); r[1] = f2bf((float)a[1]);
        r[2] = f2bf((float)a[2]); r[3] = f2bf((float)a[3]);
        r[4] = f2bf((float)b[0]); r[5] = f2bf((float)b[1]);
        r[6] = f2bf((float)b[2]); r[7] = f2bf((float)b[3]);
        *(bf16x8*)(o + i) = r;
    }
}

__device__ __forceinline__ void load_lds16(const void* g, void* l) {
    __builtin_amdgcn_global_load_lds((const __attribute__((address_space(1))) void*)g,
                                     (__attribute__((address_space(3))) void*)l, 16, 0, 0);
}

#define BAR() do { __builtin_amdgcn_s_barrier(); __builtin_amdgcn_sched_barrier(0); } while (0)
#define VM(n) do { asm volatile("s_waitcnt vmcnt(" #n ")" ::: "memory"); __builtin_amdgcn_sched_barrier(0); } while (0)

// ============ 256x256 8-phase GEMM (T1+T2+T3+T4+T5) ============
// C[m][n] = sum_k A[m][k]*B[n][k]; epilogue y = acc*scales[n]+bias[n].
// LDS: lds[buf][region][128*64] bf16; regions: 0=A-mh0, 1=A-mh1, 2=B-nh0, 3=B-nh1.
//   A region q rows: {wm0 rows q*64..q*64+63} then {wm1 rows 128+q*64..}, i.e.
//   ht-row = wm*64 + r.  B region nh cols: ht-row = wn*32 + c (c<32).
// 16B k-slots XOR-swizzled with (ht-row & 7); realized via pre-swizzled global src.
// 8 phases / 2 K-tiles; stage 1 half-tile per phase; vmcnt(6) at P4/P8 only.
__global__ __launch_bounds__(512, 2)
void gemm8p(const short* __restrict__ A, const short* __restrict__ Bw,
            const float* __restrict__ scales, const float* __restrict__ bias,
            float* __restrict__ out) {
    __shared__ short lds[2][4][128 * 64];   // 128 KiB

    const int tid  = threadIdx.x;
    const int lane = tid & 63;
    const int w    = tid >> 6;     // 0..7
    const int wm   = w >> 2;       // 0..1
    const int wn   = w & 3;        // 0..3
    const int lrow = lane & 15;
    const int lkg  = lane >> 4;
    const int sx   = lane & 7;

    // XCD-bijective block swizzle (nwg = 1024, divisible by 8)
    const int nwg = gridDim.x;
    const int swz = (blockIdx.x & 7) * (nwg >> 3) + (blockIdx.x >> 3);
    const int bn  = (swz & 15) * 256;          // N/256 = 16
    const int bm  = (swz >> 4) * 256;

    // staging geometry: chunk c = L*512+tid -> ht-row=c>>3, lds slot=c&7,
    // global k-chunk kc = slot ^ (row&7)
    const short* aS[2];
    const short* bS[2];
#pragma unroll
    for (int L = 0; L < 2; ++L) {
        const int c   = L * 512 + tid;
        const int row = c >> 3;
        const int kc  = (c & 7) ^ (row & 7);
        const int mA  = bm + ((row >> 6) << 7) + (row & 63);   // + q*64 via ptr offset
        const int nB  = bn + ((row >> 5) << 6) + (row & 31);   // + nh*32 via ptr offset
        aS[L] = A  + (size_t)mA * K_DIM + kc * 8;
        bS[L] = Bw + (size_t)nB * K_DIM + kc * 8;
    }
    const int wofs = w << 9;   // wave-uniform lds base (shorts) for L=0

#define STAGE_A(buf, q, kt) do { \
    short* d = &lds[buf][q][wofs]; \
    const long ko = (long)(kt) * 64 + (long)(q) * (64 * (long)K_DIM); \
    load_lds16(aS[0] + ko, d); \
    load_lds16(aS[1] + ko, d + 4096); \
} while (0)

#define STAGE_B(buf, nh, kt) do { \
    short* d = &lds[buf][2 + (nh)][wofs]; \
    const long ko = (long)(kt) * 64 + (long)(nh) * (32 * (long)K_DIM); \
    load_lds16(bS[0] + ko, d); \
    load_lds16(bS[1] + ko, d + 4096); \
} while (0)

    const int aoff = (wm << 6) + lrow;   // + sub*16
    const int boff = (wn << 5) + lrow;   // + sub*16

#define RD_A(buf, q, sub, ks) \
    (*(const bf16x8*)&lds[buf][q][((aoff + (sub) * 16) << 6) + (((((ks) << 2) + lkg) ^ sx) << 3)])
#define RD_B(buf, nh, sub, ks) \
    (*(const bf16x8*)&lds[buf][2 + (nh)][((boff + (sub) * 16) << 6) + (((((ks) << 2) + lkg) ^ sx) << 3)])

    f32x4 acc[8][4];
#pragma unroll
    for (int i = 0; i < 8; ++i)
#pragma unroll
        for (int j = 0; j < 4; ++j)
            acc[i][j] = (f32x4){0.f, 0.f, 0.f, 0.f};

    bf16x8 aF[4][2], bF0[2][2], bF1[2][2];

#define LOAD_AF(buf, q) do { \
    _Pragma("unroll") for (int ii = 0; ii < 4; ++ii) { \
        aF[ii][0] = RD_A(buf, q, ii, 0); aF[ii][1] = RD_A(buf, q, ii, 1); } \
} while (0)
#define LOAD_BF(dst, buf, nh) do { \
    _Pragma("unroll") for (int jj = 0; jj < 2; ++jj) { \
        dst[jj][0] = RD_B(buf, nh, jj, 0); dst[jj][1] = RD_B(buf, nh, jj, 1); } \
} while (0)
#define MMA_Q(mh, nh, BREG) do { \
    __builtin_amdgcn_s_setprio(1); \
    _Pragma("unroll") for (int ii = 0; ii < 4; ++ii) \
    _Pragma("unroll") for (int jj = 0; jj < 2; ++jj) \
    _Pragma("unroll") for (int ks = 0; ks < 2; ++ks) \
        acc[(mh) * 4 + ii][(nh) * 2 + jj] = __builtin_amdgcn_mfma_f32_16x16x32_bf16( \
            aF[ii][ks], BREG[jj][ks], acc[(mh) * 4 + ii][(nh) * 2 + jj], 0, 0, 0); \
    __builtin_amdgcn_s_setprio(0); \
} while (0)

    // ---- prologue: tile0 -> buf0 (4 ht), tile1 -> buf1 (first 3 ht)
    STAGE_A(0, 0, 0); STAGE_A(0, 1, 0); STAGE_B(0, 0, 0); STAGE_B(0, 1, 0);
    STAGE_A(1, 0, 1); STAGE_B(1, 0, 1); STAGE_B(1, 1, 1);
    VM(6);            // tile0's 8 loads landed; 3 ht of tile1 in flight
    BAR();

    for (int it = 0; it < NT / 2; ++it) {
        const int kt  = it * 2;
        const bool s2 = (kt + 2 < NT);   // false only for kt = 62
        const bool s3 = (kt + 3 < NT);

        // P1: tile kt Q(0,0)      stage A1(kt+1)->buf1   [dead since prev P7]
        LOAD_AF(0, 0); LOAD_BF(bF0, 0, 0);
        STAGE_A(1, 1, kt + 1);
        BAR(); MMA_Q(0, 0, bF0); BAR();

        // P2: Q(0,1)              stage A0(kt+2)->buf0   [A-mh0 consumed P1]
        LOAD_BF(bF1, 0, 1);
        if (s2) STAGE_A(0, 0, kt + 2);
        BAR(); MMA_Q(0, 1, bF1); BAR();

        // P3: Q(1,0)              stage B0(kt+2)->buf0   [B-nh0 consumed P1, reg-cached]
        LOAD_AF(0, 1);
        if (s2) STAGE_B(0, 0, kt + 2);
        BAR(); MMA_Q(1, 0, bF0); BAR();

        // P4: Q(1,1)              stage B1(kt+2)->buf0   [B-nh1 consumed P2, reg-cached]
        if (s2) { STAGE_B(0, 1, kt + 2); VM(6); } else { VM(0); }
        BAR(); MMA_Q(1, 1, bF1); BAR();

        // P5: tile kt+1 Q(0,0)    stage A1(kt+2)->buf0   [A-mh1 consumed P3]
        LOAD_AF(1, 0); LOAD_BF(bF0, 1, 0);
        if (s2) STAGE_A(0, 1, kt + 2);
        BAR(); MMA_Q(0, 0, bF0); BAR();

        // P6: Q(0,1)              stage A0(kt+3)->buf1
        LOAD_BF(bF1, 1, 1);
        if (s3) STAGE_A(1, 0, kt + 3);
        BAR(); MMA_Q(0, 1, bF1); BAR();

        // P7: Q(1,0)              stage B0(kt+3)->buf1
        LOAD_AF(1, 1);
        if (s3) STAGE_B(1, 0, kt + 3);
        BAR(); MMA_Q(1, 0, bF0); BAR();

        // P8: Q(1,1)              stage B1(kt+3)->buf1
        if (s3) { STAGE_B(1, 1, kt + 3); VM(6); }
        BAR(); MMA_Q(1, 1, bF1); BAR();
    }

    // epilogue: y = acc * scales[col] + bias[col]
#pragma unroll
    for (int j = 0; j < 4; ++j) {
        const int col = bn + (wn << 6) + j * 16 + lrow;
        const float s  = scales[col];
        const float bb = bias[col];
#pragma unroll
        for (int i = 0; i < 8; ++i) {
            const int r0 = bm + (wm << 7) + i * 16 + (lkg << 2);
#pragma unroll
            for (int r = 0; r < 4; ++r)
                out[(size_t)(r0 + r) * N_DIM + col] = acc[i][j][r] * s + bb;
        }
    }
#undef STAGE_A
#undef STAGE_B
#undef RD_A
#undef RD_B
#undef LOAD_AF
#undef LOAD_BF
#undef MMA_Q
}

// ============ fallback: 128x128 reg-staged kernel (no workspace) ============
__global__ __launch_bounds__(256)
void gemm_fallback(const float* __restrict__ Xf, const int* __restrict__ Qw,
                   const float* __restrict__ scales, const float* __restrict__ bias,
                   float* __restrict__ out) {
    __shared__ short a_lds[128 * 64];
    __shared__ short b_lds[128 * 64];

    const int tid  = threadIdx.x;
    const int lane = tid & 63;
    const int wid  = tid >> 6;
    const int wm   = wid >> 1;
    const int wn   = wid & 1;
    const int bn = (blockIdx.x % (N_DIM / 128)) * 128;
    const int bm = (blockIdx.x / (N_DIM / 128)) * 128;
    const int lrow = lane & 15;
    const int lkg  = lane >> 4;

    f32x4 acc[4][4];
#pragma unroll
    for (int i = 0; i < 4; ++i)
#pragma unroll
        for (int j = 0; j < 4; ++j)
            acc[i][j] = (f32x4){0.f, 0.f, 0.f, 0.f};

    for (int k0 = 0; k0 < K_DIM; k0 += 64) {
#pragma unroll
        for (int t = 0; t < 4; ++t) {
            const int ch  = t * 256 + tid;
            const int row = ch >> 3;
            const int kc  = (ch & 7) ^ (row & 7);
            {
                const float* sa = Xf + (size_t)(bm + row) * K_DIM + k0 + kc * 8;
                f32x4 a0 = *(const f32x4*)sa;
                f32x4 a1 = *(const f32x4*)(sa + 4);
                bf16x8 r;
                r[0] = f2bf(a0[0]); r[1] = f2bf(a0[1]); r[2] = f2bf(a0[2]); r[3] = f2bf(a0[3]);
                r[4] = f2bf(a1[0]); r[5] = f2bf(a1[1]); r[6] = f2bf(a1[2]); r[7] = f2bf(a1[3]);
                *(bf16x8*)&a_lds[ch * 8] = r;
            }
            {
                const int* sb = Qw + (size_t)(bn + row) * K_DIM + k0 + kc * 8;
                i32x4 q0 = *(const i32x4*)sb;
                i32x4 q1 = *(const i32x4*)(sb + 4);
                bf16x8 r;
                r[0] = f2bf((float)q0[0]); r[1] = f2bf((float)q0[1]);
                r[2] = f2bf((float)q0[2]); r[3] = f2bf((float)q0[3]);
                r[4] = f2bf((float)q1[0]); r[5] = f2bf((float)q1[1]);
                r[6] = f2bf((float)q1[2]); r[7] = f2bf((float)q1[3]);
                *(bf16x8*)&b_lds[ch * 8] = r;
            }
        }
        __syncthreads();
#pragma unroll
        for (int ks = 0; ks < 2; ++ks) {
            const int kgl = ks * 4 + lkg;
            bf16x8 af[4], bfr[4];
#pragma unroll
            for (int i = 0; i < 4; ++i) {
                const int am = wm * 64 + i * 16 + lrow;
                af[i]  = *(const bf16x8*)&a_lds[am * 64 + ((kgl ^ (am & 7)) << 3)];
                const int bnn = wn * 64 + i * 16 + lrow;
                bfr[i] = *(const bf16x8*)&b_lds[bnn * 64 + ((kgl ^ (bnn & 7)) << 3)];
            }
#pragma unroll
            for (int i = 0; i < 4; ++i)
#pragma unroll
                for (int j = 0; j < 4; ++j)
                    acc[i][j] = __builtin_amdgcn_mfma_f32_16x16x32_bf16(af[i], bfr[j], acc[i][j], 0, 0, 0);
        }
        __syncthreads();
    }

#pragma unroll
    for (int j = 0; j < 4; ++j) {
        const int col = bn + wn * 64 + j * 16 + lrow;
        const float s  = scales[col];
        const float bb = bias[col];
#pragma unroll
        for (int i = 0; i < 4; ++i) {
            const int row0 = bm + wm * 64 + i * 16 + lkg * 4;
#pragma unroll
            for (int r = 0; r < 4; ++r)
                out[(size_t)(row0 + r) * N_DIM + col] = acc[i][j][r] * s + bb;
        }
    }
}

extern "C" void kernel_launch(void* const* d_in, const int* in_sizes, int n_in,
                              void* d_out, int out_size, void* d_ws, size_t ws_size,
                              hipStream_t stream) {
    const float* x      = (const float*)d_in[0];
    const int*   qw     = (const int*)d_in[1];
    const float* scales = (const float*)d_in[2];
    const float* bias   = (const float*)d_in[3];
    float* out = (float*)d_out;

    const size_t x_elems = (size_t)M_DIM * K_DIM;
    const size_t w_elems = (size_t)N_DIM * K_DIM;
    const size_t need    = (x_elems + w_elems) * sizeof(short);

    if (ws_size >= need) {
        short* xbf = (short*)d_ws;
        short* wbf = xbf + x_elems;
        cvt_x_kernel<<<4096, 256, 0, stream>>>(x, xbf, (long)x_elems);
        cvt_w_kernel<<<2048, 256, 0, stream>>>(qw, wbf, (long)w_elems);
        const dim3 grid((M_DIM / 256) * (N_DIM / 256));   // 1024 blocks
        gemm8p<<<grid, 512, 0, stream>>>(xbf, wbf, scales, bias, out);
    } else {
        const dim3 grid((M_DIM / 128) * (N_DIM / 128));
        gemm_fallback<<<grid, 256, 0, stream>>>(x, qw, scales, bias, out);
    }
}

// Round 3
// 344.692 us; speedup vs baseline: 2.4331x; 1.5830x over previous
//
#include <hip/hip_runtime.h>

#define M_DIM 16384
#define N_DIM 4096
#define K_DIM 4096
#define NT 32            // K_DIM / BK, BK = 128 (int8)

typedef __attribute__((ext_vector_type(4))) float f32x4;
typedef __attribute__((ext_vector_type(8))) short bf16x8;
typedef __attribute__((ext_vector_type(4))) int i32x4;

__device__ __forceinline__ short f2bf(float f) {
    unsigned int u = __builtin_bit_cast(unsigned int, f);
    u += 0x7FFFu + ((u >> 16) & 1u);
    return (short)(u >> 16);
}

// ---- per-row (token) quantize x -> int8, rs[row] = absmax/127 ----
__global__ __launch_bounds__(256)
void quant_x_kernel(const float* __restrict__ x, char* __restrict__ x8,
                    float* __restrict__ rs) {
    const int row = blockIdx.x;
    const int tid = threadIdx.x;
    const float* xr = x + (size_t)row * K_DIM;
    f32x4 v[4];
    float am = 0.f;
#pragma unroll
    for (int p = 0; p < 4; ++p) {
        v[p] = *(const f32x4*)(xr + p * 1024 + tid * 4);
#pragma unroll
        for (int e = 0; e < 4; ++e) am = fmaxf(am, fabsf(v[p][e]));
    }
#pragma unroll
    for (int off = 32; off >= 1; off >>= 1)
        am = fmaxf(am, __shfl_xor(am, off, 64));
    __shared__ float smax[4];
    if ((tid & 63) == 0) smax[tid >> 6] = am;
    __syncthreads();
    am = fmaxf(fmaxf(smax[0], smax[1]), fmaxf(smax[2], smax[3]));
    const float inv = am > 0.f ? 127.f / am : 0.f;
    if (tid == 0) rs[row] = am / 127.f;
    int* o32 = (int*)(x8 + (size_t)row * K_DIM);
#pragma unroll
    for (int p = 0; p < 4; ++p) {
        const int b0 = (int)rintf(v[p][0] * inv);
        const int b1 = (int)rintf(v[p][1] * inv);
        const int b2 = (int)rintf(v[p][2] * inv);
        const int b3 = (int)rintf(v[p][3] * inv);
        o32[p * 256 + tid] = (b0 & 255) | ((b1 & 255) << 8) | ((b2 & 255) << 16) | ((b3 & 255) << 24);
    }
}

// ---- pack int32 weights (values in [-128,127]) -> int8, exact ----
__global__ void quant_w_kernel(const int* __restrict__ q, char* __restrict__ w8, long n) {
    long i = ((long)blockIdx.x * blockDim.x + threadIdx.x) * 16;
    const long stride = (long)gridDim.x * blockDim.x * 16;
    for (; i < n; i += stride) {
        i32x4 o;
#pragma unroll
        for (int j = 0; j < 4; ++j) {
            i32x4 a = *(const i32x4*)(q + i + j * 4);
            o[j] = (a[0] & 255) | ((a[1] & 255) << 8) | ((a[2] & 255) << 16) | ((a[3] & 255) << 24);
        }
        *(i32x4*)(w8 + i) = o;
    }
}

__device__ __forceinline__ void load_lds16(const void* g, void* l) {
    __builtin_amdgcn_global_load_lds((const __attribute__((address_space(1))) void*)g,
                                     (__attribute__((address_space(3))) void*)l, 16, 0, 0);
}

// raw barrier / counted vmcnt — NO sched_barrier(0) (m141 trap)
#define BAR() __builtin_amdgcn_s_barrier()
#define VM(n) asm volatile("s_waitcnt vmcnt(" #n ")" ::: "memory")

// ============ 256x256 8-phase int8 GEMM ============
// C[m][n] = sum_k x8[m][k]*w8[n][k] (exact i32); y = C * rs[m]*scales[n] + bias[n].
// BK=128 (one i8 = one bf16's byte): LDS rows 128 B, 8 x 16B slots,
// XOR-swizzle slot ^= (ht-row & 7) via pre-swizzled global source.
// Geometry/ledger identical to the verified bf16 8-phase kernel.
__global__ __launch_bounds__(512, 2)
void gemm8p_i8(const char* __restrict__ A, const char* __restrict__ Bw,
               const float* __restrict__ rs, const float* __restrict__ scales,
               const float* __restrict__ bias, float* __restrict__ out) {
    __shared__ char lds[2][4][128 * 128];   // 128 KiB

    const int tid  = threadIdx.x;
    const int lane = tid & 63;
    const int w    = tid >> 6;
    const int wm   = w >> 2;
    const int wn   = w & 3;
    const int lrow = lane & 15;
    const int lkg  = lane >> 4;
    const int sx   = lane & 7;

    const int nwg = gridDim.x;
    const int swz = (blockIdx.x & 7) * (nwg >> 3) + (blockIdx.x >> 3);
    const int bn  = (swz & 15) * 256;
    const int bm  = (swz >> 4) * 256;

    const char* aS[2];
    const char* bS[2];
#pragma unroll
    for (int L = 0; L < 2; ++L) {
        const int c   = L * 512 + tid;
        const int row = c >> 3;
        const int kc  = (c & 7) ^ (row & 7);
        const int mA  = bm + ((row >> 6) << 7) + (row & 63);
        const int nB  = bn + ((row >> 5) << 6) + (row & 31);
        aS[L] = A  + (size_t)mA * K_DIM + kc * 16;
        bS[L] = Bw + (size_t)nB * K_DIM + kc * 16;
    }
    const int wofs = w << 10;   // wave byte base, L=0

#define STAGE_A(buf, q, kt) do { \
    char* d = &lds[buf][q][wofs]; \
    const long ko = (long)(kt) * 128 + (long)(q) * (64 * (long)K_DIM); \
    load_lds16(aS[0] + ko, d); \
    load_lds16(aS[1] + ko, d + 8192); \
} while (0)

#define STAGE_B(buf, nh, kt) do { \
    char* d = &lds[buf][2 + (nh)][wofs]; \
    const long ko = (long)(kt) * 128 + (long)(nh) * (32 * (long)K_DIM); \
    load_lds16(bS[0] + ko, d); \
    load_lds16(bS[1] + ko, d + 8192); \
} while (0)

    const int aoff = (wm << 6) + lrow;
    const int boff = (wn << 5) + lrow;

#define RD_A(buf, q, sub, ks) \
    (*(const i32x4*)&lds[buf][q][((aoff + (sub) * 16) << 7) + (((((ks) << 2) + lkg) ^ sx) << 4)])
#define RD_B(buf, nh, sub, ks) \
    (*(const i32x4*)&lds[buf][2 + (nh)][((boff + (sub) * 16) << 7) + (((((ks) << 2) + lkg) ^ sx) << 4)])

    i32x4 acc[8][4];
#pragma unroll
    for (int i = 0; i < 8; ++i)
#pragma unroll
        for (int j = 0; j < 4; ++j)
            acc[i][j] = (i32x4){0, 0, 0, 0};

    i32x4 aF[4][2], bF0[2][2], bF1[2][2];

#define LOAD_AF(buf, q) do { \
    _Pragma("unroll") for (int ii = 0; ii < 4; ++ii) { \
        aF[ii][0] = RD_A(buf, q, ii, 0); aF[ii][1] = RD_A(buf, q, ii, 1); } \
} while (0)
#define LOAD_BF(dst, buf, nh) do { \
    _Pragma("unroll") for (int jj = 0; jj < 2; ++jj) { \
        dst[jj][0] = RD_B(buf, nh, jj, 0); dst[jj][1] = RD_B(buf, nh, jj, 1); } \
} while (0)
#define MMA_Q(mh, nh, BREG) do { \
    __builtin_amdgcn_s_setprio(1); \
    _Pragma("unroll") for (int ii = 0; ii < 4; ++ii) \
    _Pragma("unroll") for (int jj = 0; jj < 2; ++jj) \
    _Pragma("unroll") for (int ks = 0; ks < 2; ++ks) \
        acc[(mh) * 4 + ii][(nh) * 2 + jj] = __builtin_amdgcn_mfma_i32_16x16x64_i8( \
            aF[ii][ks], BREG[jj][ks], acc[(mh) * 4 + ii][(nh) * 2 + jj], 0, 0, 0); \
    __builtin_amdgcn_s_setprio(0); \
} while (0)

    // prologue: tile0 -> buf0 (4 ht), tile1 -> buf1 (first 3 ht)
    STAGE_A(0, 0, 0); STAGE_A(0, 1, 0); STAGE_B(0, 0, 0); STAGE_B(0, 1, 0);
    STAGE_A(1, 0, 1); STAGE_B(1, 0, 1); STAGE_B(1, 1, 1);
    VM(6);
    BAR();

    for (int it = 0; it < NT / 2; ++it) {
        const int kt  = it * 2;
        const bool s2 = (kt + 2 < NT);
        const bool s3 = (kt + 3 < NT);

        // P1
        LOAD_AF(0, 0); LOAD_BF(bF0, 0, 0);
        STAGE_A(1, 1, kt + 1);
        BAR(); MMA_Q(0, 0, bF0); BAR();
        // P2
        LOAD_BF(bF1, 0, 1);
        if (s2) STAGE_A(0, 0, kt + 2);
        BAR(); MMA_Q(0, 1, bF1); BAR();
        // P3
        LOAD_AF(0, 1);
        if (s2) STAGE_B(0, 0, kt + 2);
        BAR(); MMA_Q(1, 0, bF0); BAR();
        // P4
        if (s2) { STAGE_B(0, 1, kt + 2); VM(6); } else { VM(0); }
        BAR(); MMA_Q(1, 1, bF1); BAR();
        // P5
        LOAD_AF(1, 0); LOAD_BF(bF0, 1, 0);
        if (s2) STAGE_A(0, 1, kt + 2);
        BAR(); MMA_Q(0, 0, bF0); BAR();
        // P6
        LOAD_BF(bF1, 1, 1);
        if (s3) STAGE_A(1, 0, kt + 3);
        BAR(); MMA_Q(0, 1, bF1); BAR();
        // P7
        LOAD_AF(1, 1);
        if (s3) STAGE_B(1, 0, kt + 3);
        BAR(); MMA_Q(1, 0, bF0); BAR();
        // P8
        if (s3) { STAGE_B(1, 1, kt + 3); VM(6); }
        BAR(); MMA_Q(1, 1, bF1); BAR();
    }

    // epilogue: y = idot * (rs[row] * scales[col]) + bias[col]  (fp32 exact path)
#pragma unroll
    for (int i = 0; i < 8; ++i) {
        const int r0 = bm + (wm << 7) + i * 16 + (lkg << 2);
        const f32x4 rsv = *(const f32x4*)&rs[r0];
#pragma unroll
        for (int j = 0; j < 4; ++j) {
            const int col = bn + (wn << 6) + j * 16 + lrow;
            const float sc = scales[col];
            const float bb = bias[col];
#pragma unroll
            for (int r = 0; r < 4; ++r)
                out[(size_t)(r0 + r) * N_DIM + col] = (float)acc[i][j][r] * (rsv[r] * sc) + bb;
        }
    }
#undef STAGE_A
#undef STAGE_B
#undef RD_A
#undef RD_B
#undef LOAD_AF
#undef LOAD_BF
#undef MMA_Q
}

// ============ fallback (ws too small): reg-staged bf16, known-correct ============
__global__ __launch_bounds__(256)
void gemm_fallback(const float* __restrict__ Xf, const int* __restrict__ Qw,
                   const float* __restrict__ scales, const float* __restrict__ bias,
                   float* __restrict__ out) {
    __shared__ short a_lds[128 * 64];
    __shared__ short b_lds[128 * 64];
    const int tid  = threadIdx.x;
    const int lane = tid & 63;
    const int wid  = tid >> 6;
    const int wm   = wid >> 1;
    const int wn   = wid & 1;
    const int bn = (blockIdx.x % (N_DIM / 128)) * 128;
    const int bm = (blockIdx.x / (N_DIM / 128)) * 128;
    const int lrow = lane & 15;
    const int lkg  = lane >> 4;

    f32x4 acc[4][4];
#pragma unroll
    for (int i = 0; i < 4; ++i)
#pragma unroll
        for (int j = 0; j < 4; ++j)
            acc[i][j] = (f32x4){0.f, 0.f, 0.f, 0.f};

    for (int k0 = 0; k0 < K_DIM; k0 += 64) {
#pragma unroll
        for (int t = 0; t < 4; ++t) {
            const int ch  = t * 256 + tid;
            const int row = ch >> 3;
            const int kc  = (ch & 7) ^ (row & 7);
            {
                const float* sa = Xf + (size_t)(bm + row) * K_DIM + k0 + kc * 8;
                f32x4 a0 = *(const f32x4*)sa;
                f32x4 a1 = *(const f32x4*)(sa + 4);
                bf16x8 r;
                r[0] = f2bf(a0[0]); r[1] = f2bf(a0[1]); r[2] = f2bf(a0[2]); r[3] = f2bf(a0[3]);
                r[4] = f2bf(a1[0]); r[5] = f2bf(a1[1]); r[6] = f2bf(a1[2]); r[7] = f2bf(a1[3]);
                *(bf16x8*)&a_lds[ch * 8] = r;
            }
            {
                const int* sb = Qw + (size_t)(bn + row) * K_DIM + k0 + kc * 8;
                i32x4 q0 = *(const i32x4*)sb;
                i32x4 q1 = *(const i32x4*)(sb + 4);
                bf16x8 r;
                r[0] = f2bf((float)q0[0]); r[1] = f2bf((float)q0[1]);
                r[2] = f2bf((float)q0[2]); r[3] = f2bf((float)q0[3]);
                r[4] = f2bf((float)q1[0]); r[5] = f2bf((float)q1[1]);
                r[6] = f2bf((float)q1[2]); r[7] = f2bf((float)q1[3]);
                *(bf16x8*)&b_lds[ch * 8] = r;
            }
        }
        __syncthreads();
#pragma unroll
        for (int ks = 0; ks < 2; ++ks) {
            const int kgl = ks * 4 + lkg;
            bf16x8 af[4], bfr[4];
#pragma unroll
            for (int i = 0; i < 4; ++i) {
                const int am = wm * 64 + i * 16 + lrow;
                af[i]  = *(const bf16x8*)&a_lds[am * 64 + ((kgl ^ (am & 7)) << 3)];
                const int bnn = wn * 64 + i * 16 + lrow;
                bfr[i] = *(const bf16x8*)&b_lds[bnn * 64 + ((kgl ^ (bnn & 7)) << 3)];
            }
#pragma unroll
            for (int i = 0; i < 4; ++i)
#pragma unroll
                for (int j = 0; j < 4; ++j)
                    acc[i][j] = __builtin_amdgcn_mfma_f32_16x16x32_bf16(af[i], bfr[j], acc[i][j], 0, 0, 0);
        }
        __syncthreads();
    }
#pragma unroll
    for (int j = 0; j < 4; ++j) {
        const int col = bn + wn * 64 + j * 16 + lrow;
        const float s  = scales[col];
        const float bb = bias[col];
#pragma unroll
        for (int i = 0; i < 4; ++i) {
            const int row0 = bm + wm * 64 + i * 16 + lkg * 4;
#pragma unroll
            for (int r = 0; r < 4; ++r)
                out[(size_t)(row0 + r) * N_DIM + col] = acc[i][j][r] * s + bb;
        }
    }
}

extern "C" void kernel_launch(void* const* d_in, const int* in_sizes, int n_in,
                              void* d_out, int out_size, void* d_ws, size_t ws_size,
                              hipStream_t stream) {
    const float* x      = (const float*)d_in[0];
    const int*   qw     = (const int*)d_in[1];
    const float* scales = (const float*)d_in[2];
    const float* bias   = (const float*)d_in[3];
    float* out = (float*)d_out;

    const size_t x_elems = (size_t)M_DIM * K_DIM;   // 64 MB as i8
    const size_t w_elems = (size_t)N_DIM * K_DIM;   // 16 MB as i8
    const size_t need    = x_elems + w_elems + M_DIM * sizeof(float);

    if (ws_size >= need) {
        char*  x8 = (char*)d_ws;
        char*  w8 = x8 + x_elems;
        float* rs = (float*)(w8 + w_elems);
        quant_x_kernel<<<M_DIM, 256, 0, stream>>>(x, x8, rs);
        quant_w_kernel<<<2048, 256, 0, stream>>>(qw, w8, (long)w_elems);
        const dim3 grid((M_DIM / 256) * (N_DIM / 256));   // 1024 blocks
        gemm8p_i8<<<grid, 512, 0, stream>>>(x8, w8, rs, scales, bias, out);
    } else {
        const dim3 grid((M_DIM / 128) * (N_DIM / 128));
        gemm_fallback<<<grid, 256, 0, stream>>>(x, qw, scales, bias, out);
    }
}